// Round 6
// baseline (1496.468 us; speedup 1.0000x reference)
//
#include <hip/hip_runtime.h>
#include <hip/hip_bf16.h>

#define NXD 512
#define NYD 512
#define TD 5
#define BD 4
#define HIDD 64
#define PLANE (NXD*NYD)      /* 262144 */
#define VOL (TD*PLANE)       /* 1310720 */
#define NBLK 1024            /* persistent grid: 4 tiles per block */

typedef __bf16 bf16x8 __attribute__((ext_vector_type(8)));
typedef __bf16 bf16x4 __attribute__((ext_vector_type(4)));
typedef float  f32x4  __attribute__((ext_vector_type(4)));

// LDS strides: sx 16 B/pixel; sh 80 B/pixel (group stride 5, coprime with 8).
#define SX_PS 16
#define SH_PS 80

// W1r: [kt=3][ch=64][32 bf16]   k = tap*8 + c8   (taps 9..11 zero-padded)
// W2r: [h=2][tap=9][out=16][32] k(within half) = c32; out 5..15 zero
#define W1R_ELEMS (3*64*32)   /* 6144 */
#define W2R_ELEMS (2*9*16*32) /* 9216 */

__global__ __launch_bounds__(256)
void prep_weights(const float* __restrict__ W1, const float* __restrict__ W2,
                  __bf16* __restrict__ W1r, __bf16* __restrict__ W2r)
{
    int id = blockIdx.x * 256 + threadIdx.x;
    if (id < W1R_ELEMS) {
        int kt  = id >> 11;
        int rem = id & 2047;
        int n   = rem >> 5;
        int kk  = rem & 31;
        int k   = kt * 32 + kk;
        int tap = k >> 3, c = k & 7;
        float v = 0.f;
        if (tap <= 8 && c < 5)
            v = W1[(n * 5 + c) * 9 + tap];      // W1 [64][5][3][3]
        W1r[id] = (__bf16)v;
    } else if (id < W1R_ELEMS + W2R_ELEMS) {
        int id2 = id - W1R_ELEMS;
        int h    = id2 / 4608;
        int rem  = id2 - h * 4608;
        int tap  = rem >> 9;
        int rem2 = rem & 511;
        int n    = rem2 >> 5;
        int c    = rem2 & 31;
        float v = 0.f;
        if (n < 5)
            v = W2[(n * HIDD + h * 32 + c) * 9 + tap];  // W2 [5][64][3][3]
        W2r[id2] = (__bf16)v;
    }
}

// zero the grid-barrier counter each launch (workspace may be re-poisoned).
__global__ void zero_bar(unsigned* bar) { if (threadIdx.x == 0) bar[0] = 0u; }

// Monotonic-counter grid barrier.  Co-residency of all NBLK blocks is
// guaranteed: LDS 32768 B -> 5 blocks/CU capacity (1280) >= 1024, and
// __launch_bounds__(256,4) caps VGPR so >=4 blocks/CU always fit.
// target derived from own arrival -> replay-safe, no reset race.
__device__ __forceinline__ void grid_barrier(unsigned* cnt)
{
    __syncthreads();
    if (threadIdx.x == 0) {
        __threadfence();   // release: make this block's stores visible device-wide
        unsigned arr = __hip_atomic_fetch_add(cnt, 1u, __ATOMIC_ACQ_REL,
                                              __HIP_MEMORY_SCOPE_AGENT);
        unsigned target = (arr & ~(unsigned)(NBLK - 1)) + (unsigned)NBLK;
        while (__hip_atomic_load(cnt, __ATOMIC_RELAXED,
                                 __HIP_MEMORY_SCOPE_AGENT) < target)
            __builtin_amdgcn_s_sleep(2);
        __threadfence();   // acquire: invalidate caches before reading halos
    }
    __syncthreads();
}

// ---------------------------------------------------------------------------
// Persistent fused solver: 5 phi iterations + cost rows, one kernel.
// Per-tile body is the r4 kernel verbatim (573us version: no swizzle, no
// setprio, 60 VGPR, no spill).  1024 blocks x 4 tiles; grid barrier between
// iterations replaces 4 launch ramps + drains; iter 5 is cost-only (x5),
// replacing cost_kernel.
// LDS = 6400 (sx 20x20) + 25920 (sh) = 32320 -> 32768 granule -> 5 blk/CU.
// ---------------------------------------------------------------------------
__global__ __launch_bounds__(256, 4)
void phi_fused(const float* __restrict__ x0,
               const __bf16* __restrict__ W1r, const __bf16* __restrict__ W2r,
               const float* __restrict__ b1, const float* __restrict__ b2,
               const float* __restrict__ gt, const float* __restrict__ yobs,
               const int* __restrict__ mask,
               float* __restrict__ out_x, float* __restrict__ wsA,
               float* __restrict__ cpart, unsigned* __restrict__ bar)
{
    __shared__ __align__(16) char sx[400 * SX_PS];  // 6400 B (20x20 tile)
    __shared__ __align__(16) char sh[324 * SH_PS];  // 25920 B

    const int tid   = threadIdx.x;
    const int wv    = tid >> 6;
    const int lane  = tid & 63;
    const int l15   = lane & 15;
    const int quad  = lane >> 4;
    const size_t PROW = (size_t)BD * 4096 * 3;

    #pragma unroll 1
    for (int iter = 0; iter < 6; ++iter) {
        const float* xin; float* xo; float* crow;
        int blend = 1, costonly = 0;
        switch (iter) {
        case 0:  xin = x0;    xo = out_x; crow = cpart + 0 * PROW; break;
        case 1:  xin = out_x; xo = wsA;   crow = cpart + 1 * PROW; break;
        case 2:  xin = wsA;   xo = out_x; crow = cpart + 2 * PROW; break;
        case 3:  xin = out_x; xo = wsA;   crow = cpart + 3 * PROW; break;
        case 4:  xin = wsA;   xo = out_x; crow = nullptr; blend = 0; break;
        default: xin = out_x; xo = nullptr; crow = cpart + 4 * PROW;
                 costonly = 1; break;
        }

        #pragma unroll 1
        for (int s = 0; s < 4; ++s) {
            const int t   = (int)blockIdx.x * 4 + s;   // tile id 0..4095
            const int b   = t >> 10;
            const int cid = t & 1023;
            const int gy0 = (cid >> 5) * 16;
            const int gx0 = (cid & 31) * 16;
            const float* xb = xin + (size_t)b * VOL;

            // ---- stage x tile 20x20 (halo 2): one b128 write per pixel ----
            for (int p = tid; p < 400; p += 256) {
                const int u  = p / 20;
                const int v  = p - u * 20;
                const int gx = gx0 + u - 2;
                const int gy = gy0 + v - 2;
                bf16x8 pix = {(__bf16)0.f,(__bf16)0.f,(__bf16)0.f,(__bf16)0.f,
                              (__bf16)0.f,(__bf16)0.f,(__bf16)0.f,(__bf16)0.f};
                if (gx >= 0 && gx < NXD && gy >= 0 && gy < NYD) {
                    const float* src = xb + (size_t)gx * NYD + gy;
                    #pragma unroll
                    for (int c = 0; c < TD; ++c) pix[c] = (__bf16)src[(size_t)c * PLANE];
                }
                *(bf16x8*)(sx + p * SX_PS) = pix;
            }
            __syncthreads();

            // ---- fused cost of xin (rows 0..3, and row 4 in cost-only) ----
            if (crow) {
                const int ti = tid >> 4, tj = tid & 15;
                const int u  = ti + 2,  v  = tj + 2;
                const size_t gbase = (size_t)b * VOL + (size_t)(gx0 + ti) * NYD + (gy0 + tj);
                float mse = 0.f, dy = 0.f, q = 0.f;
                #pragma unroll
                for (int c = 0; c < TD; ++c) {
                    const size_t gi = gbase + (size_t)c * PLANE;
                    const float vv = xin[gi];                 // fp32 (L2-hot)
                    const float g  = gt[gi];
                    const float yo = yobs[gi];
                    const int   m  = mask[gi];
                    mse += (g - vv) * (g - vv);
                    float d = vv - yo;
                    if (m) dy += d * d;
                    float xp1 = (float)*(const __bf16*)(sx + (u * 20 + v + 1) * SX_PS + c * 2);
                    float yp1 = (float)*(const __bf16*)(sx + ((u + 1) * 20 + v) * SX_PS + c * 2);
                    float tp1 = (c < TD - 1)
                              ? (float)*(const __bf16*)(sx + (u * 20 + v) * SX_PS + (c + 1) * 2)
                              : 0.f;
                    q += 6.01f * vv * vv - 2.f * vv * (xp1 + yp1 + tp1);
                }
                #pragma unroll
                for (int off = 32; off > 0; off >>= 1) {
                    mse += __shfl_xor(mse, off, 64);
                    dy  += __shfl_xor(dy,  off, 64);
                    q   += __shfl_xor(q,   off, 64);
                }
                if (lane == 0) {
                    float* pp = crow + ((size_t)t * 4 + wv) * 3;
                    pp[0] = mse; pp[1] = dy; pp[2] = q;
                }
            }

            if (costonly) { __syncthreads(); continue; }  // sx WAR before next stage

            f32x4 acc2[4] = {{0.f,0.f,0.f,0.f},{0.f,0.f,0.f,0.f},
                             {0.f,0.f,0.f,0.f},{0.f,0.f,0.f,0.f}};

            for (int half = 0; half < 2; ++half) {
                // ---- conv1 A (weight) frags + bias ----
                bf16x8 A1[2][3];
                f32x4  bias1[2];
                #pragma unroll
                for (int mt = 0; mt < 2; ++mt) {
                    bias1[mt] = *(const f32x4*)(b1 + half * 32 + mt * 16 + quad * 4);
                    #pragma unroll
                    for (int kt = 0; kt < 3; ++kt)
                        A1[mt][kt] = *(const bf16x8*)(W1r +
                            ((size_t)(kt * 64 + half * 32 + mt * 16 + l15) * 32 + quad * 8));
                }
                if (half) __syncthreads();   // prev conv2 reads of sh done

                // ---- conv1: 6 pixel n-tiles per wave ----
                #pragma unroll 2
                for (int nt = 0; nt < 6; ++nt) {
                    const int ntg = wv * 6 + nt;
                    const int p   = ntg * 16 + l15;   // pixel in padded 384 n-space
                    const int pc  = (p < 324) ? p : 323;
                    const int i   = pc / 18;
                    const int j   = pc - 18 * i;
                    const int pb  = (i * 20 + j) * SX_PS;
                    bf16x8 Bx[3];
                    #pragma unroll
                    for (int kt = 0; kt < 3; ++kt) {
                        int tap = kt * 4 + quad;
                        if (tap > 8) tap = 8;   // pad taps: weights zero, clamp addr
                        Bx[kt] = *(const bf16x8*)(sx + pb + ((tap / 3) * 20 + tap % 3) * SX_PS);
                    }
                    #pragma unroll
                    for (int mt = 0; mt < 2; ++mt) {
                        f32x4 a = {0.f, 0.f, 0.f, 0.f};
                        #pragma unroll
                        for (int kt = 0; kt < 3; ++kt)
                            a = __builtin_amdgcn_mfma_f32_16x16x32_bf16(
                                    A1[mt][kt], Bx[kt], a, 0, 0, 0);
                        if (p < 324) {
                            bf16x4 hv;
                            #pragma unroll
                            for (int r = 0; r < 4; ++r)
                                hv[r] = (__bf16)fmaxf(a[r] + bias1[mt][r], 0.f);
                            *(bf16x4*)(sh + p * SH_PS + (mt * 16 + quad * 4) * 2) = hv;
                        }
                    }
                }
                __syncthreads();

                // ---- conv2: rolling 6-row x 3-shift window ----
                bf16x8 A2[9];
                #pragma unroll
                for (int tap = 0; tap < 9; ++tap)
                    A2[tap] = *(const bf16x8*)(W2r +
                        ((size_t)((half * 9 + tap) * 16 + l15) * 32 + quad * 8));

                const int shbase = (wv * 4 * 18 + l15) * SH_PS + quad * 16;
                bf16x8 R[6][3];
                #pragma unroll
                for (int rr = 0; rr < 3; ++rr)
                    #pragma unroll
                    for (int tx = 0; tx < 3; ++tx)
                        R[rr][tx] = *(const bf16x8*)(sh + shbase + (rr * 18 + tx) * SH_PS);
                #pragma unroll
                for (int m = 0; m < 4; ++m) {
                    #pragma unroll
                    for (int dy = 0; dy < 3; ++dy)
                        #pragma unroll
                        for (int tx = 0; tx < 3; ++tx)
                            acc2[m] = __builtin_amdgcn_mfma_f32_16x16x32_bf16(
                                          A2[dy * 3 + tx], R[m + dy][tx], acc2[m], 0, 0, 0);
                    if (m < 3) {
                        #pragma unroll
                        for (int tx = 0; tx < 3; ++tx)
                            R[m + 3][tx] = *(const bf16x8*)(sh + shbase +
                                                            ((m + 3) * 18 + tx) * SH_PS);
                    }
                }
            }

            // ---- epilogue: D row = out-channel, col = pixel ----
            float b2v[4];
            #pragma unroll
            for (int r = 0; r < 4; ++r) {
                const int ch = quad * 4 + r;
                b2v[r] = (ch < TD) ? b2[ch] : 0.f;
            }
            #pragma unroll
            for (int m = 0; m < 4; ++m) {
                const int ti2 = wv * 4 + m;
                const size_t rowoff = (size_t)b * VOL + (size_t)(gx0 + ti2) * NYD + (gy0 + l15);
                #pragma unroll
                for (int r = 0; r < 4; ++r) {
                    const int ch = quad * 4 + r;
                    if (ch < TD) {
                        const size_t off = rowoff + (size_t)ch * PLANE;
                        float o = acc2[m][r] + b2v[r];
                        if (blend && mask[off]) o = yobs[off];
                        xo[off] = o;
                    }
                }
            }
        }

        if (iter < 5) grid_barrier(bar);
        else break;
    }
}

// cpart layout: [row r=0..4][b=0..3][4096][3].  out cmp_loss [B=4][5][2].
__global__ __launch_bounds__(256)
void finalize_kernel(const float* __restrict__ cpart,
                     float* __restrict__ out)
{
    const int r = blockIdx.x / BD;
    const int b = blockIdx.x - r * BD;
    const float* base = cpart + ((size_t)r * BD + b) * 4096 * 3;
    float mse = 0.f, dy = 0.f, q = 0.f;
    for (int k = threadIdx.x; k < 4096; k += 256) {
        mse += base[k * 3 + 0];
        dy  += base[k * 3 + 1];
        q   += base[k * 3 + 2];
    }
    #pragma unroll
    for (int off = 32; off > 0; off >>= 1) {
        mse += __shfl_xor(mse, off, 64);
        dy  += __shfl_xor(dy,  off, 64);
        q   += __shfl_xor(q,   off, 64);
    }
    __shared__ float red[3][4];
    const int wave = threadIdx.x >> 6;
    const int lane = threadIdx.x & 63;
    if (lane == 0) { red[0][wave] = mse; red[1][wave] = dy; red[2][wave] = q; }
    __syncthreads();
    if (threadIdx.x == 0) {
        float m  = red[0][0] + red[0][1] + red[0][2] + red[0][3];
        float d  = red[1][0] + red[1][1] + red[1][2] + red[1][3];
        float qq = red[2][0] + red[2][1] + red[2][2] + red[2][3];
        out[b * 10 + r * 2 + 0] = m / (float)VOL;
        out[b * 10 + r * 2 + 1] = 1000.f * d + qq;
    }
}

extern "C" void kernel_launch(void* const* d_in, const int* in_sizes, int n_in,
                              void* d_out, int out_size, void* d_ws, size_t ws_size,
                              hipStream_t stream)
{
    const float* gt   = (const float*)d_in[0];
    const float* x0   = (const float*)d_in[1];
    const float* yobs = (const float*)d_in[2];
    const int*   mask = (const int*)d_in[3];
    const float* W1   = (const float*)d_in[4];
    const float* b1   = (const float*)d_in[5];
    const float* W2   = (const float*)d_in[6];
    const float* b2   = (const float*)d_in[7];

    float* out_x    = (float*)d_out;
    float* out_loss = out_x + (size_t)BD * VOL;

    float* wsA      = (float*)d_ws;                   // ping buffer (21 MB)
    float* cpart    = wsA + (size_t)BD * VOL;         // 5*4*4096*3 floats
    __bf16* W1r     = (__bf16*)(cpart + 5 * BD * 4096 * 3);
    __bf16* W2r     = W1r + W1R_ELEMS;
    unsigned* bar   = (unsigned*)(W2r + W2R_ELEMS);   // grid-barrier counter

    prep_weights<<<dim3(60), dim3(256), 0, stream>>>(W1, W2, W1r, W2r);
    zero_bar<<<dim3(1), dim3(64), 0, stream>>>(bar);

    phi_fused<<<dim3(NBLK), dim3(256), 0, stream>>>(
        x0, W1r, W2r, b1, b2, gt, yobs, mask, out_x, wsA, cpart, bar);

    finalize_kernel<<<dim3(5 * BD), dim3(256), 0, stream>>>(cpart, out_loss);
}

// Round 7
// 580.124 us; speedup vs baseline: 2.5796x; 2.5796x over previous
//
#include <hip/hip_runtime.h>
#include <hip/hip_bf16.h>

#define NXD 512
#define NYD 512
#define TD 5
#define BD 4
#define HIDD 64
#define PLANE (NXD*NYD)      /* 262144 */
#define VOL (TD*PLANE)       /* 1310720 */
#define CBLK 1024            /* cost blocks per batch (matches phi grid) */

typedef __bf16 bf16x8 __attribute__((ext_vector_type(8)));
typedef __bf16 bf16x4 __attribute__((ext_vector_type(4)));
typedef float  f32x4  __attribute__((ext_vector_type(4)));

// LDS strides: sx 16 B/pixel; sh 80 B/pixel (group stride 5, coprime with 8).
#define SX_PS 16
#define SH_PS 80

// W1r: [kt=3][ch=64][32 bf16]   k = tap*8 + c8   (taps 9..11 zero-padded)
// W2r: [h=2][tap=9][out=16][32] k(within half) = c32; out 5..15 zero
#define W1R_ELEMS (3*64*32)   /* 6144 */
#define W2R_ELEMS (2*9*16*32) /* 9216 */

__global__ __launch_bounds__(256)
void prep_weights(const float* __restrict__ W1, const float* __restrict__ W2,
                  __bf16* __restrict__ W1r, __bf16* __restrict__ W2r)
{
    int id = blockIdx.x * 256 + threadIdx.x;
    if (id < W1R_ELEMS) {
        int kt  = id >> 11;
        int rem = id & 2047;
        int n   = rem >> 5;
        int kk  = rem & 31;
        int k   = kt * 32 + kk;
        int tap = k >> 3, c = k & 7;
        float v = 0.f;
        if (tap <= 8 && c < 5)
            v = W1[(n * 5 + c) * 9 + tap];      // W1 [64][5][3][3]
        W1r[id] = (__bf16)v;
    } else if (id < W1R_ELEMS + W2R_ELEMS) {
        int id2 = id - W1R_ELEMS;
        int h    = id2 / 4608;
        int rem  = id2 - h * 4608;
        int tap  = rem >> 9;
        int rem2 = rem & 511;
        int n    = rem2 >> 5;
        int c    = rem2 & 31;
        float v = 0.f;
        if (n < 5)
            v = W2[(n * HIDD + h * 32 + c) * 9 + tap];  // W2 [5][64][3][3]
        W2r[id2] = (__bf16)v;
    }
}

// ---------------------------------------------------------------------------
// Fused phi (+ optional cost of its INPUT tile).  Structure identical to the
// r4 kernel (573us) except ONE change: the cost section is hoisted ABOVE the
// staging __syncthreads and made independent of sx (neighbors via shfl_down
// in the wave's 4x16 footprint; guarded global loads on edge lanes).  Its
// ~20 global loads issue alongside the staging loads and its registers die
// at the barrier, so post-barrier the block enters conv1 immediately instead
// of serializing a full memory-latency + 18-shfl chain first.
// Conv pipeline, LDS layout, epilogue: byte-identical to r4 (60-VGPR, no
// spill schedule).  LDS = 6400 + 25920 = 32320 -> 32768 -> 5 blocks/CU.
// ---------------------------------------------------------------------------
__global__ __launch_bounds__(256, 4)
void phi_mfma(const float* __restrict__ xin,
              const __bf16* __restrict__ W1r, const __bf16* __restrict__ W2r,
              const float* __restrict__ b1, const float* __restrict__ b2,
              const float* __restrict__ gt, const float* __restrict__ yobs,
              const int* __restrict__ mask,
              float* __restrict__ xout, float* __restrict__ cpart, int blend)
{
    __shared__ __align__(16) char sx[400 * SX_PS];  // 6400 B (20x20 tile)
    __shared__ __align__(16) char sh[324 * SH_PS];  // 25920 B

    const int tid   = threadIdx.x;
    const int wv    = tid >> 6;
    const int lane  = tid & 63;
    const int l15   = lane & 15;
    const int quad  = lane >> 4;
    const int b     = blockIdx.z;
    const int gx0   = blockIdx.x * 16;
    const int gy0   = blockIdx.y * 16;
    const float* xb = xin + (size_t)b * VOL;

    // ---- stage x tile 20x20 (halo 2): one b128 write per pixel ----
    for (int p = tid; p < 400; p += 256) {
        const int u  = p / 20;
        const int v  = p - u * 20;
        const int gx = gx0 + u - 2;
        const int gy = gy0 + v - 2;
        bf16x8 pix = {(__bf16)0.f,(__bf16)0.f,(__bf16)0.f,(__bf16)0.f,
                      (__bf16)0.f,(__bf16)0.f,(__bf16)0.f,(__bf16)0.f};
        if (gx >= 0 && gx < NXD && gy >= 0 && gy < NYD) {
            const float* src = xb + (size_t)gx * NYD + gy;
            #pragma unroll
            for (int c = 0; c < TD; ++c) pix[c] = (__bf16)src[(size_t)c * PLANE];
        }
        *(bf16x8*)(sx + p * SX_PS) = pix;
    }

    // ---- fused cost of the INPUT x (rows 0..3): PRE-barrier, sx-free ----
    // Loads overlap the staging loads; all cost registers dead at the sync.
    if (cpart) {
        const int ti = tid >> 4, tj = tid & 15;
        const int gx = gx0 + ti, gy = gy0 + tj;
        const size_t gbase = (size_t)b * VOL + (size_t)gx * NYD + gy;
        float xv[TD];
        #pragma unroll
        for (int c = 0; c < TD; ++c) xv[c] = xin[gbase + (size_t)c * PLANE];
        float mse = 0.f, dyv = 0.f, qv = 0.f;
        #pragma unroll
        for (int c = 0; c < TD; ++c) {
            const size_t gi = gbase + (size_t)c * PLANE;
            const float v  = xv[c];
            const float g  = gt[gi];
            const float yo = yobs[gi];
            const int   m  = mask[gi];
            mse += (g - v) * (g - v);
            float d = v - yo;
            if (m) dyv += d * d;
            // Q cross-terms: t-neighbor in-register; y/x neighbors via shfl
            // (lane+1 / lane+16 within the wave's 4x16 sub-tile), guarded
            // global load only on the sub-tile edge lanes.
            float nb = (c < TD - 1) ? xv[c + 1] : 0.f;
            float ny = __shfl_down(xv[c], 1, 64);
            float nx = __shfl_down(xv[c], 16, 64);
            if (tj == 15)      ny = (gy + 1 < NYD) ? xin[gi + 1]   : 0.f;
            if ((ti & 3) == 3) nx = (gx + 1 < NXD) ? xin[gi + NYD] : 0.f;
            qv += 6.01f * v * v - 2.f * v * (nb + ny + nx);
        }
        #pragma unroll
        for (int off = 32; off > 0; off >>= 1) {
            mse += __shfl_xor(mse, off, 64);
            dyv += __shfl_xor(dyv, off, 64);
            qv  += __shfl_xor(qv,  off, 64);
        }
        if (lane == 0) {
            float* pp = cpart + (((size_t)b * 1024 + blockIdx.y * 32 + blockIdx.x) * 4 + wv) * 3;
            pp[0] = mse; pp[1] = dyv; pp[2] = qv;
        }
    }

    __syncthreads();

    f32x4 acc2[4] = {{0.f,0.f,0.f,0.f},{0.f,0.f,0.f,0.f},
                     {0.f,0.f,0.f,0.f},{0.f,0.f,0.f,0.f}};

    for (int half = 0; half < 2; ++half) {
        // ---- conv1 A (weight) frags + bias ----
        bf16x8 A1[2][3];
        f32x4  bias1[2];
        #pragma unroll
        for (int mt = 0; mt < 2; ++mt) {
            bias1[mt] = *(const f32x4*)(b1 + half * 32 + mt * 16 + quad * 4);
            #pragma unroll
            for (int kt = 0; kt < 3; ++kt)
                A1[mt][kt] = *(const bf16x8*)(W1r +
                    ((size_t)(kt * 64 + half * 32 + mt * 16 + l15) * 32 + quad * 8));
        }
        if (half) __syncthreads();   // prev conv2 reads of sh done

        // ---- conv1: 6 pixel n-tiles per wave ----
        #pragma unroll 2
        for (int nt = 0; nt < 6; ++nt) {
            const int ntg = wv * 6 + nt;
            const int p   = ntg * 16 + l15;   // pixel in padded 384 n-space
            const int pc  = (p < 324) ? p : 323;  // clamp pad lanes (write-guarded)
            const int i   = pc / 18;
            const int j   = pc - 18 * i;
            const int pb  = (i * 20 + j) * SX_PS;
            bf16x8 Bx[3];
            #pragma unroll
            for (int kt = 0; kt < 3; ++kt) {
                int tap = kt * 4 + quad;
                if (tap > 8) tap = 8;         // pad taps: weights zero, clamp addr
                Bx[kt] = *(const bf16x8*)(sx + pb + ((tap / 3) * 20 + tap % 3) * SX_PS);
            }
            #pragma unroll
            for (int mt = 0; mt < 2; ++mt) {
                f32x4 a = {0.f, 0.f, 0.f, 0.f};
                #pragma unroll
                for (int kt = 0; kt < 3; ++kt)
                    a = __builtin_amdgcn_mfma_f32_16x16x32_bf16(
                            A1[mt][kt], Bx[kt], a, 0, 0, 0);
                if (p < 324) {
                    bf16x4 hv;
                    #pragma unroll
                    for (int r = 0; r < 4; ++r)
                        hv[r] = (__bf16)fmaxf(a[r] + bias1[mt][r], 0.f);
                    *(bf16x4*)(sh + p * SH_PS + (mt * 16 + quad * 4) * 2) = hv;
                }
            }
        }
        __syncthreads();

        // ---- conv2: rolling 6-row x 3-shift window ----
        bf16x8 A2[9];
        #pragma unroll
        for (int tap = 0; tap < 9; ++tap)
            A2[tap] = *(const bf16x8*)(W2r +
                ((size_t)((half * 9 + tap) * 16 + l15) * 32 + quad * 8));

        const int shbase = (wv * 4 * 18 + l15) * SH_PS + quad * 16;
        bf16x8 R[6][3];
        #pragma unroll
        for (int rr = 0; rr < 3; ++rr)
            #pragma unroll
            for (int tx = 0; tx < 3; ++tx)
                R[rr][tx] = *(const bf16x8*)(sh + shbase + (rr * 18 + tx) * SH_PS);
        #pragma unroll
        for (int m = 0; m < 4; ++m) {
            #pragma unroll
            for (int dy = 0; dy < 3; ++dy)
                #pragma unroll
                for (int tx = 0; tx < 3; ++tx)
                    acc2[m] = __builtin_amdgcn_mfma_f32_16x16x32_bf16(
                                  A2[dy * 3 + tx], R[m + dy][tx], acc2[m], 0, 0, 0);
            if (m < 3) {
                #pragma unroll
                for (int tx = 0; tx < 3; ++tx)
                    R[m + 3][tx] = *(const bf16x8*)(sh + shbase +
                                                    ((m + 3) * 18 + tx) * SH_PS);
            }
        }
    }

    // ---- epilogue: D row = out-channel, col = pixel ----
    float b2v[4];
    #pragma unroll
    for (int r = 0; r < 4; ++r) {
        const int ch = quad * 4 + r;
        b2v[r] = (ch < TD) ? b2[ch] : 0.f;
    }
    #pragma unroll
    for (int m = 0; m < 4; ++m) {
        const int ti2 = wv * 4 + m;
        const size_t rowoff = (size_t)b * VOL + (size_t)(gx0 + ti2) * NYD + (gy0 + l15);
        #pragma unroll
        for (int r = 0; r < 4; ++r) {
            const int ch = quad * 4 + r;
            if (ch < TD) {
                const size_t off = rowoff + (size_t)ch * PLANE;
                float o = acc2[m][r] + b2v[r];
                if (blend && mask[off]) o = yobs[off];
                xout[off] = o;
            }
        }
    }
}

// ---------------------------------------------------------------------------
// Standalone cost (for x5 only). Grid (1024, BD); per-wave partials.
// ---------------------------------------------------------------------------
__global__ __launch_bounds__(256)
void cost_kernel(const float* __restrict__ x, const float* __restrict__ gt,
                 const float* __restrict__ yobs, const int* __restrict__ mask,
                 float* __restrict__ partial)
{
    const int b  = blockIdx.y;
    const size_t bbase = (size_t)b * VOL;

    float mse = 0.f, dy = 0.f, q = 0.f;
    for (int idx = blockIdx.x * 256 + threadIdx.x; idx < VOL; idx += CBLK * 256) {
        const size_t gi = bbase + idx;
        const int t   = idx / PLANE;
        const int rem = idx - t * PLANE;
        const int i   = rem / NYD;
        const int j   = rem - i * NYD;

        const float v  = x[gi];
        const float g  = gt[gi];
        const float yo = yobs[gi];
        const int   m  = mask[gi];

        mse += (g - v) * (g - v);
        float d = v - yo;
        if (m) dy += d * d;
        float qq = 6.01f * v * v;
        if (t < TD - 1)  qq -= 2.f * v * x[gi + PLANE];
        if (i < NXD - 1) qq -= 2.f * v * x[gi + NYD];
        if (j < NYD - 1) qq -= 2.f * v * x[gi + 1];
        q += qq;
    }

    #pragma unroll
    for (int off = 32; off > 0; off >>= 1) {
        mse += __shfl_xor(mse, off, 64);
        dy  += __shfl_xor(dy,  off, 64);
        q   += __shfl_xor(q,   off, 64);
    }
    const int wave = threadIdx.x >> 6;
    const int lane = threadIdx.x & 63;
    if (lane == 0) {
        float* p = partial + (((size_t)b * CBLK + blockIdx.x) * 4 + wave) * 3;
        p[0] = mse; p[1] = dy; p[2] = q;
    }
}

// cpart layout: [row r=0..4][b=0..3][4096][3].  out cmp_loss [B=4][5][2].
__global__ __launch_bounds__(256)
void finalize_kernel(const float* __restrict__ cpart,
                     float* __restrict__ out)
{
    const int r = blockIdx.x / BD;
    const int b = blockIdx.x - r * BD;
    const float* base = cpart + ((size_t)r * BD + b) * 4096 * 3;
    float mse = 0.f, dy = 0.f, q = 0.f;
    for (int k = threadIdx.x; k < 4096; k += 256) {
        mse += base[k * 3 + 0];
        dy  += base[k * 3 + 1];
        q   += base[k * 3 + 2];
    }
    #pragma unroll
    for (int off = 32; off > 0; off >>= 1) {
        mse += __shfl_xor(mse, off, 64);
        dy  += __shfl_xor(dy,  off, 64);
        q   += __shfl_xor(q,   off, 64);
    }
    __shared__ float red[3][4];
    const int wave = threadIdx.x >> 6;
    const int lane = threadIdx.x & 63;
    if (lane == 0) { red[0][wave] = mse; red[1][wave] = dy; red[2][wave] = q; }
    __syncthreads();
    if (threadIdx.x == 0) {
        float m  = red[0][0] + red[0][1] + red[0][2] + red[0][3];
        float d  = red[1][0] + red[1][1] + red[1][2] + red[1][3];
        float qq = red[2][0] + red[2][1] + red[2][2] + red[2][3];
        out[b * 10 + r * 2 + 0] = m / (float)VOL;
        out[b * 10 + r * 2 + 1] = 1000.f * d + qq;
    }
}

extern "C" void kernel_launch(void* const* d_in, const int* in_sizes, int n_in,
                              void* d_out, int out_size, void* d_ws, size_t ws_size,
                              hipStream_t stream)
{
    const float* gt   = (const float*)d_in[0];
    const float* x0   = (const float*)d_in[1];
    const float* yobs = (const float*)d_in[2];
    const int*   mask = (const int*)d_in[3];
    const float* W1   = (const float*)d_in[4];
    const float* b1   = (const float*)d_in[5];
    const float* W2   = (const float*)d_in[6];
    const float* b2   = (const float*)d_in[7];

    float* out_x    = (float*)d_out;
    float* out_loss = out_x + (size_t)BD * VOL;

    float* wsA      = (float*)d_ws;                   // ping buffer (21 MB)
    float* cpart    = wsA + (size_t)BD * VOL;         // 5*4*4096*3 floats
    __bf16* W1r     = (__bf16*)(cpart + 5 * BD * 4096 * 3);
    __bf16* W2r     = W1r + W1R_ELEMS;
    const size_t PROW = (size_t)BD * 4096 * 3;        // per-row stride

    dim3 pgrid(NXD / 16, NYD / 16, BD), pblock(256);
    dim3 cgrid(CBLK, BD), cblock(256);

    prep_weights<<<dim3(60), dim3(256), 0, stream>>>(W1, W2, W1r, W2r);

    // x1..x4 blended, each phi also computes cost of its INPUT (rows 0..3)
    phi_mfma<<<pgrid, pblock, 0, stream>>>(x0,   W1r, W2r, b1, b2, gt, yobs, mask, out_x, cpart + 0 * PROW, 1);
    phi_mfma<<<pgrid, pblock, 0, stream>>>(out_x,W1r, W2r, b1, b2, gt, yobs, mask, wsA,   cpart + 1 * PROW, 1);
    phi_mfma<<<pgrid, pblock, 0, stream>>>(wsA,  W1r, W2r, b1, b2, gt, yobs, mask, out_x, cpart + 2 * PROW, 1);
    phi_mfma<<<pgrid, pblock, 0, stream>>>(out_x,W1r, W2r, b1, b2, gt, yobs, mask, wsA,   cpart + 3 * PROW, 1);
    // x5 = phi(x4), no blend, no fused cost
    phi_mfma<<<pgrid, pblock, 0, stream>>>(wsA,  W1r, W2r, b1, b2, gt, yobs, mask, out_x, nullptr, 0);
    // cost(x5) -> row 4
    cost_kernel<<<cgrid, cblock, 0, stream>>>(out_x, gt, yobs, mask, cpart + 4 * PROW);

    finalize_kernel<<<dim3(5 * BD), dim3(256), 0, stream>>>(cpart, out_loss);
}

// Round 8
// 543.728 us; speedup vs baseline: 2.7522x; 1.0669x over previous
//
#include <hip/hip_runtime.h>
#include <hip/hip_bf16.h>

#define NXD 512
#define NYD 512
#define TD 5
#define BD 4
#define HIDD 64
#define PLANE (NXD*NYD)      /* 262144 */
#define VOL (TD*PLANE)       /* 1310720 */
#define CBLK 1024            /* cost blocks per batch (matches phi grid) */

typedef __bf16 bf16x8 __attribute__((ext_vector_type(8)));
typedef __bf16 bf16x4 __attribute__((ext_vector_type(4)));
typedef float  f32x4  __attribute__((ext_vector_type(4)));

// LDS strides: sx 16 B/pixel; sh 80 B/pixel (group stride 5, coprime with 8).
#define SX_PS 16
#define SH_PS 80

// W1r: [kt=3][ch=64][32 bf16]   k = tap*8 + c8   (taps 9..11 zero-padded)
// W2r: [h=2][tap=9][out=16][32] k(within half) = c32; out 5..15 zero
#define W1R_ELEMS (3*64*32)   /* 6144 */
#define W2R_ELEMS (2*9*16*32) /* 9216 */

__global__ __launch_bounds__(256)
void prep_weights(const float* __restrict__ W1, const float* __restrict__ W2,
                  __bf16* __restrict__ W1r, __bf16* __restrict__ W2r)
{
    int id = blockIdx.x * 256 + threadIdx.x;
    if (id < W1R_ELEMS) {
        int kt  = id >> 11;
        int rem = id & 2047;
        int n   = rem >> 5;
        int kk  = rem & 31;
        int k   = kt * 32 + kk;
        int tap = k >> 3, c = k & 7;
        float v = 0.f;
        if (tap <= 8 && c < 5)
            v = W1[(n * 5 + c) * 9 + tap];      // W1 [64][5][3][3]
        W1r[id] = (__bf16)v;
    } else if (id < W1R_ELEMS + W2R_ELEMS) {
        int id2 = id - W1R_ELEMS;
        int h    = id2 / 4608;
        int rem  = id2 - h * 4608;
        int tap  = rem >> 9;
        int rem2 = rem & 511;
        int n    = rem2 >> 5;
        int c    = rem2 & 31;
        float v = 0.f;
        if (n < 5)
            v = W2[(n * HIDD + h * 32 + c) * 9 + tap];  // W2 [5][64][3][3]
        W2r[id2] = (__bf16)v;
    }
}

// ---------------------------------------------------------------------------
// Fused phi (+ optional cost of its INPUT tile).  r4 structure (573us), with
// intermediates x1..x4 carried as PACKED bf16x8 per pixel ([b][x][y][8],
// 5 ch + 3 pad, 16 B):
//  * INP=1: stage = ONE global_load_dwordx4 per pixel (was 5 scattered 4-B
//    loads + 5 cvt); cost reads its 5 channels with one 16-B load.
//  * OUTP=1: epilogue packs per-pixel via one __shfl (ch4 from quad 1) and
//    stores 16 B from quad-0 lanes (was 20 scattered 4-B stores).
//  * Conv results are BIT-IDENTICAL to r4 (conv always consumed bf16 x);
//    only cost rows 1..3 see bf16-rounded x (~0.03% of loss_OI).
// Conv pipeline / barriers / LDS layout byte-identical to r4.
// LDS = 6400 + 25920 = 32320 -> 32768 -> 5 blocks/CU.
// ---------------------------------------------------------------------------
template<int INP, int OUTP>
__global__ __launch_bounds__(256, 4)
void phi_mfma(const float* __restrict__ xin,
              const __bf16* __restrict__ xin_pk,
              const __bf16* __restrict__ W1r, const __bf16* __restrict__ W2r,
              const float* __restrict__ b1, const float* __restrict__ b2,
              const float* __restrict__ gt, const float* __restrict__ yobs,
              const int* __restrict__ mask,
              float* __restrict__ xout, __bf16* __restrict__ xout_pk,
              float* __restrict__ cpart, int blend)
{
    __shared__ __align__(16) char sx[400 * SX_PS];  // 6400 B (20x20 tile)
    __shared__ __align__(16) char sh[324 * SH_PS];  // 25920 B

    const int tid   = threadIdx.x;
    const int wv    = tid >> 6;
    const int lane  = tid & 63;
    const int l15   = lane & 15;
    const int quad  = lane >> 4;
    const int b     = blockIdx.z;
    const int gx0   = blockIdx.x * 16;
    const int gy0   = blockIdx.y * 16;

    // ---- stage x tile 20x20 (halo 2): one b128 write per pixel ----
    for (int p = tid; p < 400; p += 256) {
        const int u  = p / 20;
        const int v  = p - u * 20;
        const int gx = gx0 + u - 2;
        const int gy = gy0 + v - 2;
        bf16x8 pix = {(__bf16)0.f,(__bf16)0.f,(__bf16)0.f,(__bf16)0.f,
                      (__bf16)0.f,(__bf16)0.f,(__bf16)0.f,(__bf16)0.f};
        if (gx >= 0 && gx < NXD && gy >= 0 && gy < NYD) {
            if constexpr (INP == 0) {
                const float* src = xin + (size_t)b * VOL + (size_t)gx * NYD + gy;
                #pragma unroll
                for (int c = 0; c < TD; ++c) pix[c] = (__bf16)src[(size_t)c * PLANE];
            } else {
                pix = *(const bf16x8*)(xin_pk +
                        ((size_t)b * PLANE + (size_t)gx * NYD + gy) * 8);
            }
        }
        *(bf16x8*)(sx + p * SX_PS) = pix;
    }
    __syncthreads();

    // ---- fused cost of the INPUT x (rows 0..3) ----
    if (cpart) {
        const int ti = tid >> 4, tj = tid & 15;
        const int u  = ti + 2,  v  = tj + 2;
        const size_t gbase = (size_t)b * VOL + (size_t)(gx0 + ti) * NYD + (gy0 + tj);
        float xv[TD];
        if constexpr (INP == 0) {
            #pragma unroll
            for (int c = 0; c < TD; ++c) xv[c] = xin[gbase + (size_t)c * PLANE];
        } else {
            bf16x8 pxv = *(const bf16x8*)(xin_pk +
                ((size_t)b * PLANE + (size_t)(gx0 + ti) * NYD + (gy0 + tj)) * 8);
            #pragma unroll
            for (int c = 0; c < TD; ++c) xv[c] = (float)pxv[c];
        }
        float mse = 0.f, dy = 0.f, q = 0.f;
        #pragma unroll
        for (int c = 0; c < TD; ++c) {
            const size_t gi = gbase + (size_t)c * PLANE;
            const float vv = xv[c];
            const float g  = gt[gi];
            const float yo = yobs[gi];
            const int   m  = mask[gi];
            mse += (g - vv) * (g - vv);
            float d = vv - yo;
            if (m) dy += d * d;
            // neighbors from bf16 tile (q is ~0.5% of the loss; bf16 is fine;
            // zero-halo makes boundary terms vanish automatically)
            float xp1 = (float)*(const __bf16*)(sx + (u * 20 + v + 1) * SX_PS + c * 2);
            float yp1 = (float)*(const __bf16*)(sx + ((u + 1) * 20 + v) * SX_PS + c * 2);
            float tp1 = (c < TD - 1)
                      ? (float)*(const __bf16*)(sx + (u * 20 + v) * SX_PS + (c + 1) * 2)
                      : 0.f;
            q += 6.01f * vv * vv - 2.f * vv * (xp1 + yp1 + tp1);
        }
        #pragma unroll
        for (int off = 32; off > 0; off >>= 1) {
            mse += __shfl_xor(mse, off, 64);
            dy  += __shfl_xor(dy,  off, 64);
            q   += __shfl_xor(q,   off, 64);
        }
        if (lane == 0) {
            float* pp = cpart + (((size_t)b * 1024 + blockIdx.y * 32 + blockIdx.x) * 4 + wv) * 3;
            pp[0] = mse; pp[1] = dy; pp[2] = q;
        }
    }

    f32x4 acc2[4] = {{0.f,0.f,0.f,0.f},{0.f,0.f,0.f,0.f},
                     {0.f,0.f,0.f,0.f},{0.f,0.f,0.f,0.f}};

    for (int half = 0; half < 2; ++half) {
        // ---- conv1 A (weight) frags + bias ----
        bf16x8 A1[2][3];
        f32x4  bias1[2];
        #pragma unroll
        for (int mt = 0; mt < 2; ++mt) {
            bias1[mt] = *(const f32x4*)(b1 + half * 32 + mt * 16 + quad * 4);
            #pragma unroll
            for (int kt = 0; kt < 3; ++kt)
                A1[mt][kt] = *(const bf16x8*)(W1r +
                    ((size_t)(kt * 64 + half * 32 + mt * 16 + l15) * 32 + quad * 8));
        }
        if (half) __syncthreads();   // prev conv2 reads of sh done

        // ---- conv1: 6 pixel n-tiles per wave ----
        #pragma unroll 2
        for (int nt = 0; nt < 6; ++nt) {
            const int ntg = wv * 6 + nt;
            const int p   = ntg * 16 + l15;   // pixel in padded 384 n-space
            const int pc  = (p < 324) ? p : 323;  // clamp pad lanes (write-guarded)
            const int i   = pc / 18;
            const int j   = pc - 18 * i;
            const int pb  = (i * 20 + j) * SX_PS;
            bf16x8 Bx[3];
            #pragma unroll
            for (int kt = 0; kt < 3; ++kt) {
                int tap = kt * 4 + quad;
                if (tap > 8) tap = 8;         // pad taps: weights zero, clamp addr
                Bx[kt] = *(const bf16x8*)(sx + pb + ((tap / 3) * 20 + tap % 3) * SX_PS);
            }
            #pragma unroll
            for (int mt = 0; mt < 2; ++mt) {
                f32x4 a = {0.f, 0.f, 0.f, 0.f};
                #pragma unroll
                for (int kt = 0; kt < 3; ++kt)
                    a = __builtin_amdgcn_mfma_f32_16x16x32_bf16(
                            A1[mt][kt], Bx[kt], a, 0, 0, 0);
                if (p < 324) {
                    bf16x4 hv;
                    #pragma unroll
                    for (int r = 0; r < 4; ++r)
                        hv[r] = (__bf16)fmaxf(a[r] + bias1[mt][r], 0.f);
                    *(bf16x4*)(sh + p * SH_PS + (mt * 16 + quad * 4) * 2) = hv;
                }
            }
        }
        __syncthreads();

        // ---- conv2: rolling 6-row x 3-shift window ----
        bf16x8 A2[9];
        #pragma unroll
        for (int tap = 0; tap < 9; ++tap)
            A2[tap] = *(const bf16x8*)(W2r +
                ((size_t)((half * 9 + tap) * 16 + l15) * 32 + quad * 8));

        const int shbase = (wv * 4 * 18 + l15) * SH_PS + quad * 16;
        bf16x8 R[6][3];
        #pragma unroll
        for (int rr = 0; rr < 3; ++rr)
            #pragma unroll
            for (int tx = 0; tx < 3; ++tx)
                R[rr][tx] = *(const bf16x8*)(sh + shbase + (rr * 18 + tx) * SH_PS);
        #pragma unroll
        for (int m = 0; m < 4; ++m) {
            #pragma unroll
            for (int dy = 0; dy < 3; ++dy)
                #pragma unroll
                for (int tx = 0; tx < 3; ++tx)
                    acc2[m] = __builtin_amdgcn_mfma_f32_16x16x32_bf16(
                                  A2[dy * 3 + tx], R[m + dy][tx], acc2[m], 0, 0, 0);
            if (m < 3) {
                #pragma unroll
                for (int tx = 0; tx < 3; ++tx)
                    R[m + 3][tx] = *(const bf16x8*)(sh + shbase +
                                                    ((m + 3) * 18 + tx) * SH_PS);
            }
        }
    }

    // ---- epilogue: D row = out-channel, col = pixel ----
    float b2v[4];
    #pragma unroll
    for (int r = 0; r < 4; ++r) {
        const int ch = quad * 4 + r;
        b2v[r] = (ch < TD) ? b2[ch] : 0.f;
    }
    if constexpr (OUTP == 0) {
        #pragma unroll
        for (int m = 0; m < 4; ++m) {
            const int ti2 = wv * 4 + m;
            const size_t rowoff = (size_t)b * VOL + (size_t)(gx0 + ti2) * NYD + (gy0 + l15);
            #pragma unroll
            for (int r = 0; r < 4; ++r) {
                const int ch = quad * 4 + r;
                if (ch < TD) {
                    const size_t off = rowoff + (size_t)ch * PLANE;
                    float o = acc2[m][r] + b2v[r];
                    if (blend && mask[off]) o = yobs[off];
                    xout[off] = o;
                }
            }
        }
    } else {
        const float b2_4 = b2[4];
        #pragma unroll
        for (int m = 0; m < 4; ++m) {
            const int ti2 = wv * 4 + m;
            // ch4 of row ti2, col l15 lives in quad-1 lane (16+l15), reg 0.
            const float c4 = __shfl(acc2[m][0], 16 + l15, 64) + b2_4;
            if (quad == 0) {
                const size_t poff = (size_t)b * VOL +
                                    (size_t)(gx0 + ti2) * NYD + (gy0 + l15);
                float o[TD];
                #pragma unroll
                for (int r = 0; r < 4; ++r) o[r] = acc2[m][r] + b2v[r];
                o[4] = c4;
                if (blend) {
                    #pragma unroll
                    for (int ch = 0; ch < TD; ++ch) {
                        const size_t off = poff + (size_t)ch * PLANE;
                        if (mask[off]) o[ch] = yobs[off];
                    }
                }
                bf16x8 pk = {(__bf16)o[0], (__bf16)o[1], (__bf16)o[2],
                             (__bf16)o[3], (__bf16)o[4],
                             (__bf16)0.f, (__bf16)0.f, (__bf16)0.f};
                *(bf16x8*)(xout_pk + ((size_t)b * PLANE +
                    (size_t)(gx0 + ti2) * NYD + (gy0 + l15)) * 8) = pk;
            }
        }
    }
}

// ---------------------------------------------------------------------------
// Standalone cost (for x5 only). Grid (1024, BD); per-wave partials.
// ---------------------------------------------------------------------------
__global__ __launch_bounds__(256)
void cost_kernel(const float* __restrict__ x, const float* __restrict__ gt,
                 const float* __restrict__ yobs, const int* __restrict__ mask,
                 float* __restrict__ partial)
{
    const int b  = blockIdx.y;
    const size_t bbase = (size_t)b * VOL;

    float mse = 0.f, dy = 0.f, q = 0.f;
    for (int idx = blockIdx.x * 256 + threadIdx.x; idx < VOL; idx += CBLK * 256) {
        const size_t gi = bbase + idx;
        const int t   = idx / PLANE;
        const int rem = idx - t * PLANE;
        const int i   = rem / NYD;
        const int j   = rem - i * NYD;

        const float v  = x[gi];
        const float g  = gt[gi];
        const float yo = yobs[gi];
        const int   m  = mask[gi];

        mse += (g - v) * (g - v);
        float d = v - yo;
        if (m) dy += d * d;
        float qq = 6.01f * v * v;
        if (t < TD - 1)  qq -= 2.f * v * x[gi + PLANE];
        if (i < NXD - 1) qq -= 2.f * v * x[gi + NYD];
        if (j < NYD - 1) qq -= 2.f * v * x[gi + 1];
        q += qq;
    }

    #pragma unroll
    for (int off = 32; off > 0; off >>= 1) {
        mse += __shfl_xor(mse, off, 64);
        dy  += __shfl_xor(dy,  off, 64);
        q   += __shfl_xor(q,   off, 64);
    }
    const int wave = threadIdx.x >> 6;
    const int lane = threadIdx.x & 63;
    if (lane == 0) {
        float* p = partial + (((size_t)b * CBLK + blockIdx.x) * 4 + wave) * 3;
        p[0] = mse; p[1] = dy; p[2] = q;
    }
}

// cpart layout: [row r=0..4][b=0..3][4096][3].  out cmp_loss [B=4][5][2].
__global__ __launch_bounds__(256)
void finalize_kernel(const float* __restrict__ cpart,
                     float* __restrict__ out)
{
    const int r = blockIdx.x / BD;
    const int b = blockIdx.x - r * BD;
    const float* base = cpart + ((size_t)r * BD + b) * 4096 * 3;
    float mse = 0.f, dy = 0.f, q = 0.f;
    for (int k = threadIdx.x; k < 4096; k += 256) {
        mse += base[k * 3 + 0];
        dy  += base[k * 3 + 1];
        q   += base[k * 3 + 2];
    }
    #pragma unroll
    for (int off = 32; off > 0; off >>= 1) {
        mse += __shfl_xor(mse, off, 64);
        dy  += __shfl_xor(dy,  off, 64);
        q   += __shfl_xor(q,   off, 64);
    }
    __shared__ float red[3][4];
    const int wave = threadIdx.x >> 6;
    const int lane = threadIdx.x & 63;
    if (lane == 0) { red[0][wave] = mse; red[1][wave] = dy; red[2][wave] = q; }
    __syncthreads();
    if (threadIdx.x == 0) {
        float m  = red[0][0] + red[0][1] + red[0][2] + red[0][3];
        float d  = red[1][0] + red[1][1] + red[1][2] + red[1][3];
        float qq = red[2][0] + red[2][1] + red[2][2] + red[2][3];
        out[b * 10 + r * 2 + 0] = m / (float)VOL;
        out[b * 10 + r * 2 + 1] = 1000.f * d + qq;
    }
}

extern "C" void kernel_launch(void* const* d_in, const int* in_sizes, int n_in,
                              void* d_out, int out_size, void* d_ws, size_t ws_size,
                              hipStream_t stream)
{
    const float* gt   = (const float*)d_in[0];
    const float* x0   = (const float*)d_in[1];
    const float* yobs = (const float*)d_in[2];
    const int*   mask = (const int*)d_in[3];
    const float* W1   = (const float*)d_in[4];
    const float* b1   = (const float*)d_in[5];
    const float* W2   = (const float*)d_in[6];
    const float* b2   = (const float*)d_in[7];

    float* out_x    = (float*)d_out;
    float* out_loss = out_x + (size_t)BD * VOL;

    float* wsA      = (float*)d_ws;                   // packed ping (16.8 MB)
    float* cpart    = wsA + (size_t)BD * VOL;         // 5*4*4096*3 floats
    __bf16* W1r     = (__bf16*)(cpart + 5 * BD * 4096 * 3);
    __bf16* W2r     = W1r + W1R_ELEMS;
    const size_t PROW = (size_t)BD * 4096 * 3;        // per-row stride

    // Packed intermediate buffers: 4*262144*16 B = 16.8 MB each.
    // Pong aliases the out_x region (dead until iter 4 rewrites it fp32):
    //   x1 -> Pout, x2 -> Pws, x3 -> Pout, x4 -> Pws, x5 -> out_x (fp32).
    __bf16* Pout = (__bf16*)out_x;
    __bf16* Pws  = (__bf16*)wsA;

    dim3 pgrid(NXD / 16, NYD / 16, BD), pblock(256);
    dim3 cgrid(CBLK, BD), cblock(256);

    prep_weights<<<dim3(60), dim3(256), 0, stream>>>(W1, W2, W1r, W2r);

    phi_mfma<0,1><<<pgrid, pblock, 0, stream>>>(x0, nullptr, W1r, W2r, b1, b2,
        gt, yobs, mask, nullptr, Pout, cpart + 0 * PROW, 1);
    phi_mfma<1,1><<<pgrid, pblock, 0, stream>>>(nullptr, Pout, W1r, W2r, b1, b2,
        gt, yobs, mask, nullptr, Pws,  cpart + 1 * PROW, 1);
    phi_mfma<1,1><<<pgrid, pblock, 0, stream>>>(nullptr, Pws,  W1r, W2r, b1, b2,
        gt, yobs, mask, nullptr, Pout, cpart + 2 * PROW, 1);
    phi_mfma<1,1><<<pgrid, pblock, 0, stream>>>(nullptr, Pout, W1r, W2r, b1, b2,
        gt, yobs, mask, nullptr, Pws,  cpart + 3 * PROW, 1);
    // x5 = phi(x4), no blend, fp32 output (cost_kernel + harness consumer)
    phi_mfma<1,0><<<pgrid, pblock, 0, stream>>>(nullptr, Pws,  W1r, W2r, b1, b2,
        gt, yobs, mask, out_x, nullptr, nullptr, 0);
    // cost(x5) -> row 4
    cost_kernel<<<cgrid, cblock, 0, stream>>>(out_x, gt, yobs, mask, cpart + 4 * PROW);

    finalize_kernel<<<dim3(5 * BD), dim3(256), 0, stream>>>(cpart, out_loss);
}